// Round 1
// baseline (65.995 us; speedup 1.0000x reference)
//
#include <hip/hip_runtime.h>
#include <stdint.h>

// DSVDD fused: dist = sqrt(||phi||^2 + ||c||^2 - 2 phi.c), top-3 smallest, softmin score.
// Strategy: bf16 MFMA GEMM computing S = phi.c - ||c||^2/2 (centers folded into K-pad),
// track top-3 LARGEST S per row (== 3 smallest distances), finalize with sqrt+softmin.
// Workspace: CT[3200][128] bf16, pre-transposed + pre-XOR-swizzled (needs 819200 B of d_ws).

typedef short s16x8 __attribute__((ext_vector_type(8)));
typedef float fx4 __attribute__((ext_vector_type(4)));

#define M_TOT 3136
#define CC 112
#define N_MTILES 25  // 3200 / 128

__device__ __forceinline__ unsigned short f2bf(float x) {
  unsigned u = __float_as_uint(x);
  u += 0x7fffu + ((u >> 16) & 1u);  // RNE
  return (unsigned short)(u >> 16);
}

__device__ __forceinline__ void async16(const void* g, void* l) {
  __builtin_amdgcn_global_load_lds(
      (const __attribute__((address_space(1))) unsigned int*)g,
      (__attribute__((address_space(3))) unsigned int*)l, 16, 0, 0);
}

// insert v into descending triple (t0 >= t1 >= t2), keep 3 largest. 3 VALU ops.
#define INSERT3(T0, T1, T2, V)                                  \
  do {                                                          \
    const float _a0 = (T0), _a1 = (T1), _v = (V);               \
    (T0) = fmaxf(_a0, _v);                                      \
    (T1) = __builtin_amdgcn_fmed3f(_a0, _a1, _v);               \
    (T2) = __builtin_amdgcn_fmed3f(_a1, (T2), _v);              \
  } while (0)

// ---- prep: C_bank (112 x 3136 f32) -> CT (3200 x 128 bf16, swizzled), centers folded ----
// CT[m][k]: k=0..111 = C_bank[k][m]; k=112..115 = -||c_m||^2/8 (or -2500 sentinel); rest 0.
// Physical 16B-block index = logical_block ^ (m & 7)  (XOR swizzle for ds_read_b128).
__global__ __launch_bounds__(256) void dsvdd_prep(const float* __restrict__ Cb,
                                                  unsigned char* __restrict__ CTg) {
  const int i = threadIdx.x & 63;
  const int q = threadIdx.x >> 6;
  const int m = blockIdx.x * 64 + i;
  const bool valid = (m < M_TOT);
  __shared__ float part[4][64];
  float ss = 0.f;
  const int b0 = q * 4;
  const int nb = (q == 3) ? 2 : 4;  // blocks 14,15 are special
  for (int jb = 0; jb < nb; ++jb) {
    const int b = b0 + jb;
    float v[8];
#pragma unroll
    for (int j = 0; j < 8; ++j) {
      v[j] = valid ? Cb[(size_t)(b * 8 + j) * M_TOT + m] : 0.f;
      ss += v[j] * v[j];
    }
    uint4 pk;
    pk.x = (unsigned)f2bf(v[0]) | ((unsigned)f2bf(v[1]) << 16);
    pk.y = (unsigned)f2bf(v[2]) | ((unsigned)f2bf(v[3]) << 16);
    pk.z = (unsigned)f2bf(v[4]) | ((unsigned)f2bf(v[5]) << 16);
    pk.w = (unsigned)f2bf(v[6]) | ((unsigned)f2bf(v[7]) << 16);
    *(uint4*)(CTg + (size_t)m * 256 + ((b ^ (m & 7)) * 16)) = pk;
  }
  part[q][i] = ss;
  __syncthreads();
  if (q == 0) {
    const float c2 = part[0][i] + part[1][i] + part[2][i] + part[3][i];
    const float slot = valid ? (-0.125f * c2) : -2500.0f;  // sentinel: S = -1e4
    const unsigned sb = f2bf(slot);
    const unsigned ww = sb | (sb << 16);
    uint4 blk;
    blk.x = ww; blk.y = ww; blk.z = 0u; blk.w = 0u;
    *(uint4*)(CTg + (size_t)m * 256 + ((14 ^ (m & 7)) * 16)) = blk;
    uint4 zz;
    zz.x = zz.y = zz.z = zz.w = 0u;
    *(uint4*)(CTg + (size_t)m * 256 + ((15 ^ (m & 7)) * 16)) = zz;
  }
}

// ---- main: 128 phi-rows per block, stream 25 m-tiles of 128 ----
__global__ __launch_bounds__(256, 2) void dsvdd_main(const float* __restrict__ phi,
                                                     const unsigned char* __restrict__ CTg,
                                                     float* __restrict__ out) {
  __shared__ __align__(16) unsigned char phi_lds[128 * 256];  // [row][K=128] bf16, swizzled
  __shared__ __align__(16) unsigned char ct_lds[128 * 256];   // [m_local][K=128] bf16, swizzled
  __shared__ float feat_lds[128];
  __shared__ float merge_lds[128][8];

  const int t = threadIdx.x;
  const int lane = t & 63;
  const int w = t >> 6;
  const int wm = w & 1;   // m-half of this wave
  const int wp = w >> 1;  // phi-half of this wave
  const long rowBase = (long)blockIdx.x * 128;

  // ---- stage phi tile fp32 -> bf16 (swizzled), features in fp32 ----
  {
    const int r = t >> 1;
    const int half = t & 1;
    const float* src = phi + (rowBase + r) * CC + half * 56;
    float ss = 0.f;
#pragma unroll
    for (int j = 0; j < 7; ++j) {
      const float4 v0 = *(const float4*)(src + j * 8);
      const float4 v1 = *(const float4*)(src + j * 8 + 4);
      ss += v0.x * v0.x + v0.y * v0.y + v0.z * v0.z + v0.w * v0.w;
      ss += v1.x * v1.x + v1.y * v1.y + v1.z * v1.z + v1.w * v1.w;
      uint4 pk;
      pk.x = (unsigned)f2bf(v0.x) | ((unsigned)f2bf(v0.y) << 16);
      pk.y = (unsigned)f2bf(v0.z) | ((unsigned)f2bf(v0.w) << 16);
      pk.z = (unsigned)f2bf(v1.x) | ((unsigned)f2bf(v1.y) << 16);
      pk.w = (unsigned)f2bf(v1.z) | ((unsigned)f2bf(v1.w) << 16);
      const int b = half * 7 + j;
      *(uint4*)(phi_lds + r * 256 + ((b ^ (r & 7)) * 16)) = pk;
    }
    {  // K-pad: block14 = {1,1,1,1,0,0,0,0} (fold slots), block15 = 0
      const int b = 14 + half;
      uint4 pk;
      if (half == 0) {
        pk.x = 0x3f803f80u; pk.y = 0x3f803f80u; pk.z = 0u; pk.w = 0u;
      } else {
        pk.x = pk.y = pk.z = pk.w = 0u;
      }
      *(uint4*)(phi_lds + r * 256 + ((b ^ (r & 7)) * 16)) = pk;
    }
    ss += __shfl_xor(ss, 1);
    if (half == 0) feat_lds[r] = ss;
  }

  float t0[4], t1[4], t2[4];
#pragma unroll
  for (int pf = 0; pf < 4; ++pf) t0[pf] = t1[pf] = t2[pf] = -3.0e38f;

  // stage first CT tile (each wave copies its 8 KB)
  {
    const unsigned char* g = CTg + (size_t)w * 8192 + lane * 16;
    unsigned char* l = ct_lds + w * 8192;
#pragma unroll
    for (int ii = 0; ii < 8; ++ii) async16(g + ii * 1024, l + ii * 1024);
  }
  __syncthreads();  // drains vmcnt+lgkm, phi_lds/feat_lds/ct_lds ready

  const int cq = lane & 15;  // row-in-fragment
  const int kq = lane >> 4;  // k-quarter
  const int sw = lane & 7;   // == (frag row & 7) since frag bases are multiples of 16

  for (int mt = 0; mt < N_MTILES; ++mt) {
    fx4 acc[4][4];
    const fx4 zz = {0.f, 0.f, 0.f, 0.f};
#pragma unroll
    for (int ks = 0; ks < 4; ++ks) {
      s16x8 af[4], bg[4];
      const int pb = (ks * 4 + kq) ^ sw;
#pragma unroll
      for (int mf = 0; mf < 4; ++mf)
        af[mf] = *(const s16x8*)(ct_lds + (wm * 64 + mf * 16 + cq) * 256 + pb * 16);
#pragma unroll
      for (int pf = 0; pf < 4; ++pf)
        bg[pf] = *(const s16x8*)(phi_lds + (wp * 64 + pf * 16 + cq) * 256 + pb * 16);
#pragma unroll
      for (int mf = 0; mf < 4; ++mf)
#pragma unroll
        for (int pf = 0; pf < 4; ++pf)
          acc[mf][pf] = __builtin_amdgcn_mfma_f32_16x16x32_bf16(
              af[mf], bg[pf], (ks == 0) ? zz : acc[mf][pf], 0, 0, 0);
    }
    __syncthreads();  // all waves done reading ct_lds

    if (mt + 1 < N_MTILES) {  // issue async stage of next tile
      const unsigned char* g = CTg + (size_t)(mt + 1) * 32768 + (size_t)w * 8192 + lane * 16;
      unsigned char* l = ct_lds + w * 8192;
#pragma unroll
      for (int ii = 0; ii < 8; ++ii) async16(g + ii * 1024, l + ii * 1024);
    }

    // top-3 insert on acc (VALU; overlaps the in-flight loads)
#pragma unroll
    for (int mf = 0; mf < 4; ++mf)
#pragma unroll
      for (int pf = 0; pf < 4; ++pf)
#pragma unroll
        for (int rg = 0; rg < 4; ++rg)
          INSERT3(t0[pf], t1[pf], t2[pf], acc[mf][pf][rg]);

    if (mt + 1 < N_MTILES) __syncthreads();  // next tile landed
  }

  // ---- cross-lane merge over the 4 k-quarter groups ----
#pragma unroll
  for (int pf = 0; pf < 4; ++pf) {
#pragma unroll
    for (int off = 16; off < 64; off <<= 1) {
      const float b0 = __shfl_xor(t0[pf], off);
      const float b1 = __shfl_xor(t1[pf], off);
      const float b2 = __shfl_xor(t2[pf], off);
      INSERT3(t0[pf], t1[pf], t2[pf], b0);
      INSERT3(t0[pf], t1[pf], t2[pf], b1);
      INSERT3(t0[pf], t1[pf], t2[pf], b2);
    }
  }
  if (kq == 0) {
#pragma unroll
    for (int pf = 0; pf < 4; ++pf) {
      const int row = wp * 64 + pf * 16 + cq;
      merge_lds[row][wm * 4 + 0] = t0[pf];
      merge_lds[row][wm * 4 + 1] = t1[pf];
      merge_lds[row][wm * 4 + 2] = t2[pf];
    }
  }
  __syncthreads();

  // ---- finalize: merge m-halves, sqrt, softmin, write ----
  if (t < 128) {
    float s0 = merge_lds[t][0], s1 = merge_lds[t][1], s2 = merge_lds[t][2];
    INSERT3(s0, s1, s2, merge_lds[t][4]);
    INSERT3(s0, s1, s2, merge_lds[t][5]);
    INSERT3(s0, s1, s2, merge_lds[t][6]);
    const float feat = feat_lds[t];
    const float d0 = sqrtf(fmaxf(feat - 2.f * s0, 0.f));
    const float d1 = sqrtf(fmaxf(feat - 2.f * s1, 0.f));
    const float d2 = sqrtf(fmaxf(feat - 2.f * s2, 0.f));
    const float w0 = 1.0f / (1.0f + __expf(d0 - d1) + __expf(d0 - d2));
    out[rowBase + t] = w0 * d0;
  }
}

extern "C" void kernel_launch(void* const* d_in, const int* in_sizes, int n_in,
                              void* d_out, int out_size, void* d_ws, size_t ws_size,
                              hipStream_t stream) {
  (void)in_sizes; (void)n_in; (void)out_size; (void)ws_size;
  const float* phi = (const float*)d_in[0];
  const float* Cb = (const float*)d_in[1];
  float* out = (float*)d_out;
  unsigned char* CTg = (unsigned char*)d_ws;  // 3200*128*2 = 819200 B
  dsvdd_prep<<<50, 256, 0, stream>>>(Cb, CTg);
  dsvdd_main<<<392, 256, 0, stream>>>(phi, CTg, out);
}

// Round 2
// 65.745 us; speedup vs baseline: 1.0038x; 1.0038x over previous
//
#include <hip/hip_runtime.h>
#include <stdint.h>

// DSVDD fused: dist = sqrt(||phi||^2 + ||c||^2 - 2 phi.c), top-3 smallest, softmin score.
// bf16 MFMA GEMM computes S = phi.c - ||c||^2/2 (centers folded into K-pad 112->128),
// track top-3 LARGEST S per row, finalize with sqrt+softmin.
// R2: phi fragments held in REGISTERS (extracted once); waves own distinct 32-m slices;
// single barrier per m-tile with double-buffered CT staging. LDS 64KB dbuf + aliases.

typedef short s16x8 __attribute__((ext_vector_type(8)));
typedef float fx4 __attribute__((ext_vector_type(4)));

#define M_TOT 3136
#define CC 112
#define N_MTILES 25  // 3200 / 128

__device__ __forceinline__ unsigned short f2bf(float x) {
  unsigned u = __float_as_uint(x);
  u += 0x7fffu + ((u >> 16) & 1u);  // RNE
  return (unsigned short)(u >> 16);
}

__device__ __forceinline__ void async16(const void* g, void* l) {
  __builtin_amdgcn_global_load_lds(
      (const __attribute__((address_space(1))) unsigned int*)g,
      (__attribute__((address_space(3))) unsigned int*)l, 16, 0, 0);
}

// insert v into descending triple (t0 >= t1 >= t2), keep 3 largest. 3 VALU ops.
#define INSERT3(T0, T1, T2, V)                                  \
  do {                                                          \
    const float _a0 = (T0), _a1 = (T1), _v = (V);               \
    (T0) = fmaxf(_a0, _v);                                      \
    (T1) = __builtin_amdgcn_fmed3f(_a0, _a1, _v);               \
    (T2) = __builtin_amdgcn_fmed3f(_a1, (T2), _v);              \
  } while (0)

// ---- prep: C_bank (112 x 3136 f32) -> CT (3200 x 128 bf16, swizzled), centers folded ----
__global__ __launch_bounds__(256) void dsvdd_prep(const float* __restrict__ Cb,
                                                  unsigned char* __restrict__ CTg) {
  const int i = threadIdx.x & 63;
  const int q = threadIdx.x >> 6;
  const int m = blockIdx.x * 64 + i;
  const bool valid = (m < M_TOT);
  __shared__ float part[4][64];
  float ss = 0.f;
  const int b0 = q * 4;
  const int nb = (q == 3) ? 2 : 4;  // blocks 14,15 are special
  for (int jb = 0; jb < nb; ++jb) {
    const int b = b0 + jb;
    float v[8];
#pragma unroll
    for (int j = 0; j < 8; ++j) {
      v[j] = valid ? Cb[(size_t)(b * 8 + j) * M_TOT + m] : 0.f;
      ss += v[j] * v[j];
    }
    uint4 pk;
    pk.x = (unsigned)f2bf(v[0]) | ((unsigned)f2bf(v[1]) << 16);
    pk.y = (unsigned)f2bf(v[2]) | ((unsigned)f2bf(v[3]) << 16);
    pk.z = (unsigned)f2bf(v[4]) | ((unsigned)f2bf(v[5]) << 16);
    pk.w = (unsigned)f2bf(v[6]) | ((unsigned)f2bf(v[7]) << 16);
    *(uint4*)(CTg + (size_t)m * 256 + ((b ^ (m & 7)) * 16)) = pk;
  }
  part[q][i] = ss;
  __syncthreads();
  if (q == 0) {
    const float c2 = part[0][i] + part[1][i] + part[2][i] + part[3][i];
    const float slot = valid ? (-0.125f * c2) : -2500.0f;  // sentinel: S = -1e4
    const unsigned sb = f2bf(slot);
    const unsigned ww = sb | (sb << 16);
    uint4 blk;
    blk.x = ww; blk.y = ww; blk.z = 0u; blk.w = 0u;
    *(uint4*)(CTg + (size_t)m * 256 + ((14 ^ (m & 7)) * 16)) = blk;
    uint4 zz;
    zz.x = zz.y = zz.z = zz.w = 0u;
    *(uint4*)(CTg + (size_t)m * 256 + ((15 ^ (m & 7)) * 16)) = zz;
  }
}

// ---- main: 128 phi rows per block; wave w owns m-slice [w*32, w*32+32) of each tile ----
__global__ __launch_bounds__(256, 2) void dsvdd_main(const float* __restrict__ phi,
                                                     const unsigned char* __restrict__ CTg,
                                                     float* __restrict__ out) {
  __shared__ __align__(16) unsigned char smem[66048];
  unsigned char* const buf0 = smem;           // CT double-buffer half 0
  unsigned char* const buf1 = smem + 32768;   // CT half 1; phi staging in prologue
  float* const feat_lds = (float*)(smem + 65536);
  float(*const merge_lds)[17] = (float(*)[17])smem;  // epilogue alias (128*17*4 = 8704 B)

  const int t = threadIdx.x;
  const int lane = t & 63;
  const int w = t >> 6;
  const long rowBase = (long)blockIdx.x * 128;
  const int cq = lane & 15;  // col-in-fragment (phi row low bits / m row low bits)
  const int kq = lane >> 4;  // k-quarter
  const int sw = lane & 7;   // swizzle key == row&7 for rows == cq mod 16

  // 1) issue CT tile 0 -> buf0 (async, overlaps phi staging)
  {
    const unsigned char* g = CTg + (size_t)w * 8192 + lane * 16;
    unsigned char* l = buf0 + w * 8192;
#pragma unroll
    for (int ii = 0; ii < 8; ++ii) async16(g + ii * 1024, l + ii * 1024);
  }

  // 2) stage phi tile fp32 -> bf16 (swizzled) into buf1; features in fp32
  {
    const int r = t >> 1;
    const int half = t & 1;
    const float* src = phi + (rowBase + r) * CC + half * 56;
    float ss = 0.f;
#pragma unroll
    for (int j = 0; j < 7; ++j) {
      const float4 v0 = *(const float4*)(src + j * 8);
      const float4 v1 = *(const float4*)(src + j * 8 + 4);
      ss += v0.x * v0.x + v0.y * v0.y + v0.z * v0.z + v0.w * v0.w;
      ss += v1.x * v1.x + v1.y * v1.y + v1.z * v1.z + v1.w * v1.w;
      uint4 pk;
      pk.x = (unsigned)f2bf(v0.x) | ((unsigned)f2bf(v0.y) << 16);
      pk.y = (unsigned)f2bf(v0.z) | ((unsigned)f2bf(v0.w) << 16);
      pk.z = (unsigned)f2bf(v1.x) | ((unsigned)f2bf(v1.y) << 16);
      pk.w = (unsigned)f2bf(v1.z) | ((unsigned)f2bf(v1.w) << 16);
      const int b = half * 7 + j;
      *(uint4*)(buf1 + r * 256 + ((b ^ (r & 7)) * 16)) = pk;
    }
    {  // K-pad: block14 = {1,1,1,1,0,0,0,0} (fold slots), block15 = 0
      const int b = 14 + half;
      uint4 pk;
      if (half == 0) {
        pk.x = 0x3f803f80u; pk.y = 0x3f803f80u; pk.z = 0u; pk.w = 0u;
      } else {
        pk.x = pk.y = pk.z = pk.w = 0u;
      }
      *(uint4*)(buf1 + r * 256 + ((b ^ (r & 7)) * 16)) = pk;
    }
    ss += __shfl_xor(ss, 1);
    if (half == 0) feat_lds[r] = ss;
  }
  __syncthreads();  // CT tile 0 landed in buf0; phi landed in buf1

  // 3) extract ALL phi fragments into registers (held for whole kernel): 128 VGPRs
  s16x8 bg[4][8];
#pragma unroll
  for (int ks = 0; ks < 4; ++ks)
#pragma unroll
    for (int pf = 0; pf < 8; ++pf)
      bg[ks][pf] = *(const s16x8*)(buf1 + (pf * 16 + cq) * 256 + (((ks * 4 + kq) ^ sw) * 16));
  __syncthreads();  // everyone done reading buf1 (it becomes CT buffer for mt=1)

  float t0[8], t1[8], t2[8];
#pragma unroll
  for (int pf = 0; pf < 8; ++pf) t0[pf] = t1[pf] = t2[pf] = -3.0e38f;

  const fx4 zz = {0.f, 0.f, 0.f, 0.f};
  for (int mt = 0; mt < N_MTILES; ++mt) {
    const unsigned char* rd = smem + ((mt & 1) ? 32768 : 0);
    unsigned char* wr = smem + ((mt & 1) ? 0 : 32768);

    if (mt + 1 < N_MTILES) {  // issue next CT tile into the other buffer
      const unsigned char* g = CTg + (size_t)(mt + 1) * 32768 + (size_t)w * 8192 + lane * 16;
      unsigned char* l = wr + w * 8192;
#pragma unroll
      for (int ii = 0; ii < 8; ++ii) async16(g + ii * 1024, l + ii * 1024);
    }

#pragma unroll
    for (int mf = 0; mf < 2; ++mf) {
      s16x8 af[4];
#pragma unroll
      for (int ks = 0; ks < 4; ++ks)
        af[ks] = *(const s16x8*)(rd + (w * 32 + mf * 16 + cq) * 256 + (((ks * 4 + kq) ^ sw) * 16));
      fx4 acc[8];
#pragma unroll
      for (int ks = 0; ks < 4; ++ks)
#pragma unroll
        for (int pf = 0; pf < 8; ++pf)
          acc[pf] = __builtin_amdgcn_mfma_f32_16x16x32_bf16(
              af[ks], bg[ks][pf], (ks == 0) ? zz : acc[pf], 0, 0, 0);
#pragma unroll
      for (int pf = 0; pf < 8; ++pf)
#pragma unroll
        for (int rg = 0; rg < 4; ++rg)
          INSERT3(t0[pf], t1[pf], t2[pf], acc[pf][rg]);
    }
    __syncthreads();  // drains vmcnt (next tile landed) + everyone done reading rd
  }

  // ---- cross-lane merge over the 4 k-quarter groups (each wave covers all 128 rows) ----
#pragma unroll
  for (int pf = 0; pf < 8; ++pf) {
#pragma unroll
    for (int off = 16; off < 64; off <<= 1) {
      const float b0 = __shfl_xor(t0[pf], off);
      const float b1 = __shfl_xor(t1[pf], off);
      const float b2 = __shfl_xor(t2[pf], off);
      INSERT3(t0[pf], t1[pf], t2[pf], b0);
      INSERT3(t0[pf], t1[pf], t2[pf], b1);
      INSERT3(t0[pf], t1[pf], t2[pf], b2);
    }
  }
  // (final __syncthreads of the mt loop already ensures no one reads smem as CT anymore)
  if (kq == 0) {
#pragma unroll
    for (int pf = 0; pf < 8; ++pf) {
      const int row = pf * 16 + cq;
      merge_lds[row][w * 4 + 0] = t0[pf];
      merge_lds[row][w * 4 + 1] = t1[pf];
      merge_lds[row][w * 4 + 2] = t2[pf];
    }
  }
  __syncthreads();

  // ---- finalize: merge the 4 waves' m-slices, sqrt, softmin, write ----
  if (t < 128) {
    float s0 = merge_lds[t][0], s1 = merge_lds[t][1], s2 = merge_lds[t][2];
#pragma unroll
    for (int ww2 = 1; ww2 < 4; ++ww2) {
      INSERT3(s0, s1, s2, merge_lds[t][ww2 * 4 + 0]);
      INSERT3(s0, s1, s2, merge_lds[t][ww2 * 4 + 1]);
      INSERT3(s0, s1, s2, merge_lds[t][ww2 * 4 + 2]);
    }
    const float feat = feat_lds[t];
    const float d0 = sqrtf(fmaxf(feat - 2.f * s0, 0.f));
    const float d1 = sqrtf(fmaxf(feat - 2.f * s1, 0.f));
    const float d2 = sqrtf(fmaxf(feat - 2.f * s2, 0.f));
    const float w0 = 1.0f / (1.0f + __expf(d0 - d1) + __expf(d0 - d2));
    out[rowBase + t] = w0 * d0;
  }
}

extern "C" void kernel_launch(void* const* d_in, const int* in_sizes, int n_in,
                              void* d_out, int out_size, void* d_ws, size_t ws_size,
                              hipStream_t stream) {
  (void)in_sizes; (void)n_in; (void)out_size; (void)ws_size;
  const float* phi = (const float*)d_in[0];
  const float* Cb = (const float*)d_in[1];
  float* out = (float*)d_out;
  unsigned char* CTg = (unsigned char*)d_ws;  // 3200*128*2 = 819200 B
  dsvdd_prep<<<50, 256, 0, stream>>>(Cb, CTg);
  dsvdd_main<<<392, 256, 0, stream>>>(phi, CTg, out);
}